// Round 8
// baseline (1086.029 us; speedup 1.0000x reference)
//
#include <hip/hip_runtime.h>

#define M_ 16
#define H_ 32
#define D_ 128
#define P_ 8192
#define N_ 4096
#define PM_ 8208   // P + M

// workspace layout (float offsets) — no region needs pre-zeroing
#define WS_Q    0          // [32][16][128] q
#define WS_K    65536      // [32][16][128] new k
#define WS_V    131072     // [32][16][128] new v
#define WS_S1   196608     // [512]
#define WS_S2   197120     // [512]
#define WS_IS2  197632     // [512] 1/s2
#define WS_XQ   198144     // x_norm as float4 [1024][16]
#define WS_E2   263680     // e2t [32][8208][16] (h,p,m). noiseT pre-filled, overwritten in place.
#define WS_PP   263680     // proj partials [32][16][12288] — ALIASES E2/PO (dead before noise_t/attn)
#define WS_PO   4466176    // attn O partials [32][65][16][128]  (ends 8,726,016)
#define WS_SP1  8726016    // [32][65*4][16] s1 partials (ends 8,859,136)
#define WS_SP2  8859136    // [32][65*4][16]           (ends 8,992,256)
// total = 8,992,256 floats = 36.0 MB

typedef __attribute__((address_space(1))) const void gvoid_t;
typedef __attribute__((address_space(3))) void lvoid_t;

// ---------------- Kernel A: RMS norm ----------------
__global__ __launch_bounds__(256) void rmsnorm_kernel(const float* __restrict__ X,
                                                      float* __restrict__ ws) {
  int m = blockIdx.x, t = threadIdx.x;
  __shared__ float red[256];
  const float4* X4 = (const float4*)(X + (size_t)m * N_);
  float s = 0.f;
  #pragma unroll
  for (int q = 0; q < 4; q++) {
    float4 v = X4[t + q * 256];
    s += v.x * v.x + v.y * v.y + v.z * v.z + v.w * v.w;
  }
  red[t] = s;
  __syncthreads();
  for (int off = 128; off > 0; off >>= 1) {
    if (t < off) red[t] += red[t + off];
    __syncthreads();
  }
  float scale = rsqrtf(red[0] * (1.0f / N_));
  float4* xq = (float4*)(ws + WS_XQ);
  #pragma unroll
  for (int q = 0; q < 4; q++) {
    int nq = t + q * 256;
    float4 v = X4[nq];
    v.x *= scale; v.y *= scale; v.z *= scale; v.w *= scale;
    xq[nq * 16 + m] = v;  // xq[n/4][m]
  }
}

// ---------------- Kernel B: QKV projection (k-split x32) ----------------
__global__ __launch_bounds__(256, 4) void proj_kernel(const float* __restrict__ Wq,
                                                      const float* __restrict__ Wk,
                                                      const float* __restrict__ Wv,
                                                      const float* __restrict__ xr,
                                                      float* __restrict__ ws) {
  __shared__ float tile[4 * 2048];  // 8KB per wave
  int widx = threadIdx.x >> 6, lane = threadIdx.x & 63;
  int kc = blockIdx.x / 48;
  int jt = (blockIdx.x % 48) * 4 + widx;
  int jj0 = jt * 64;
  int sel = jj0 >> 12;
  int j0 = jj0 & 4095;
  const float* Wm = (sel == 0) ? Wq : ((sel == 1) ? Wk : Wv);
  int n0 = kc * 128;

  float* tl = tile + widx * 2048;
  int g8 = lane >> 3, c8 = lane & 7;
  int cq = c8 ^ g8;

  const float* gsrc[8];
  #pragma unroll
  for (int i = 0; i < 8; i++)
    gsrc[i] = Wm + (size_t)(j0 + i * 8 + g8) * N_ + n0 + cq * 4;

  const float4* tl4 = (const float4*)tl;
  int rbase = lane * 8;
  int swz = lane & 7;

  const float4* xr4 = (const float4*)xr;
  float acc[16];
  #pragma unroll
  for (int m = 0; m < 16; m++) acc[m] = 0.f;

  for (int ti = 0; ti < 4; ti++) {
    #pragma unroll
    for (int i = 0; i < 8; i++)
      __builtin_amdgcn_global_load_lds((gvoid_t*)(gsrc[i] + ti * 32),
                                       (lvoid_t*)(tl + i * 256), 16, 0, 0);
    asm volatile("s_waitcnt vmcnt(0)" ::: "memory");
    __builtin_amdgcn_sched_barrier(0);

    int nqb = (n0 >> 2) + ti * 8;
    #pragma unroll
    for (int k = 0; k < 8; k++) {
      float4 w4 = tl4[rbase + (k ^ swz)];
      int qbase = (nqb + k) * 16;
      #pragma unroll
      for (int m = 0; m < 16; m++) {
        float4 xm = xr4[qbase + m];
        acc[m] += xm.x * w4.x + xm.y * w4.y + xm.z * w4.z + xm.w * w4.w;
      }
    }
  }

  float* pp = ws + WS_PP + (size_t)kc * 16 * 12288 + jj0 + lane;
  #pragma unroll
  for (int m = 0; m < 16; m++) pp[(size_t)m * 12288] = acc[m];
}

// ---------------- Kernel B2: reduce proj partials over kc ----------------
__global__ __launch_bounds__(256) void proj_reduce_kernel(float* __restrict__ ws) {
  int tid = blockIdx.x * 256 + threadIdx.x;  // 0..196607
  int m = tid / 12288;
  int j = tid - m * 12288;
  float acc = 0.f;
  #pragma unroll
  for (int kc = 0; kc < 32; kc++)
    acc += ws[WS_PP + ((size_t)(kc * 16 + m)) * 12288 + j];
  int sel = j >> 12, jj = j & 4095;
  int h = jj >> 7, d = jj & 127;
  ws[WS_Q + sel * 65536 + (h * 16 + m) * 128 + d] = acc;
}

// ---------------- Kernel N: transpose noise into E2: noiseT[h][p][m] ----------------
__global__ __launch_bounds__(256) void noise_t_kernel(const float* __restrict__ noise,
                                                      float* __restrict__ ws) {
  __shared__ float tile[16 * 68];
  int blk = blockIdx.x;
  int h = blk / 129, ct = blk % 129;
  int c0 = ct * 64;
  int t = threadIdx.x;
  int rw = t >> 6, cc = t & 63;
  #pragma unroll
  for (int i = 0; i < 4; i++) {
    int m = i * 4 + rw;
    int c = c0 + cc;
    if (c < PM_) tile[m * 68 + cc] = noise[((size_t)h * 16 + m) * PM_ + c];
  }
  __syncthreads();
  float* outh = ws + WS_E2 + (size_t)h * PM_ * 16;
  #pragma unroll
  for (int i = 0; i < 4; i++) {
    int flat = i * 256 + t;         // flat = c*16 + m
    int c = flat >> 4, m = flat & 15;
    if (c0 + c < PM_) outh[(size_t)(c0 + c) * 16 + m] = tile[m * 68 + c];
  }
}

// ---------------- Kernel C1: attention main pass ----------------
// b<64: pure cacheK/cacheV provenance (no ws-derived K/V) -> loads hoist past
// e2 stores. nz preloaded for all 8 iterations BEFORE any store. b==64: tiny
// new-KV tail (ws K/V). 256 threads, launch_bounds(256,6).
__global__ __launch_bounds__(256, 6) void attn_kernel(const float* __restrict__ cacheK,
                                                      const float* __restrict__ cacheV,
                                                      const float* __restrict__ taup,
                                                      float* __restrict__ ws) {
  __shared__ float red[4 * 1088];      // stride-17 rows: conflict-free reduce
  int h = blockIdx.x / 65, b = blockIdx.x % 65;
  int widx = threadIdx.x >> 6, lane = threadIdx.x & 63;
  int m8 = lane & 7, sl = lane >> 3;
  int rsel = lane >> 4;
  bool tb = (lane >> 3) & 1;
  bool rb0 = rsel & 1, rb1 = (rsel >> 1) & 1;
  float inv_tau = 1.0f / taup[0];

  float qv[2][16];
  #pragma unroll
  for (int t = 0; t < 2; t++) {
    const float4* qp = (const float4*)(ws + WS_Q + ((size_t)(h * 16) + m8 + 8 * t) * 128 + sl * 16);
    #pragma unroll
    for (int jq = 0; jq < 4; jq++) {
      float4 v = qp[jq];
      qv[t][jq * 4] = v.x; qv[t][jq * 4 + 1] = v.y;
      qv[t][jq * 4 + 2] = v.z; qv[t][jq * 4 + 3] = v.w;
    }
  }
  float oacc[2][16];
  #pragma unroll
  for (int t = 0; t < 2; t++)
    #pragma unroll
    for (int j = 0; j < 16; j++) oacc[t][j] = 0.f;
  float s1 = 0.f, s2 = 0.f;

  float* e2g = ws + WS_E2 + (size_t)h * PM_ * 16 + lane;

  auto process = [&](int p0, const float* kb, const float* vb, float nz) {
    float pr[4][2];
    #pragma unroll
    for (int r = 0; r < 4; r++) {
      float4 kq[4];
      const float4* krp = (const float4*)(kb + r * D_ + sl * 16);
      kq[0] = krp[0]; kq[1] = krp[1]; kq[2] = krp[2]; kq[3] = krp[3];
      const float* kk = (const float*)kq;
      float t0 = 0.f, t1 = 0.f;
      #pragma unroll
      for (int j = 0; j < 16; j++) { t0 += kk[j] * qv[0][j]; t1 += kk[j] * qv[1][j]; }
      pr[r][0] = t0; pr[r][1] = t1;
    }
    float cc[4][2];
    #pragma unroll
    for (int r = 0; r < 4; r++)
      #pragma unroll
      for (int t = 0; t < 2; t++) {
        float v = pr[r][t];
        v += __shfl_xor(v, 8, 64);
        v += __shfl_xor(v, 16, 64);
        v += __shfl_xor(v, 32, 64);
        cc[r][t] = v;
      }
    // static select trees — no runtime array indexing
    float a0 = tb ? cc[0][1] : cc[0][0];
    float a1 = tb ? cc[1][1] : cc[1][0];
    float a2 = tb ? cc[2][1] : cc[2][0];
    float a3 = tb ? cc[3][1] : cc[3][0];
    float b0 = rb0 ? a1 : a0;
    float b1 = rb0 ? a3 : a2;
    float myc = rb1 ? b1 : b0;

    float e2 = __expf((myc + nz) * inv_tau);
    e2g[(size_t)p0 * 16] = e2;
    s2 += e2;

    float e1[4][2];
    #pragma unroll
    for (int r = 0; r < 4; r++) {
      e1[r][0] = __expf(cc[r][0]);
      e1[r][1] = __expf(cc[r][1]);
    }
    float f0 = tb ? e1[0][1] : e1[0][0];
    float f1 = tb ? e1[1][1] : e1[1][0];
    float f2 = tb ? e1[2][1] : e1[2][0];
    float f3 = tb ? e1[3][1] : e1[3][0];
    float g0s = rb0 ? f1 : f0;
    float g1s = rb0 ? f3 : f2;
    s1 += rb1 ? g1s : g0s;

    #pragma unroll
    for (int r = 0; r < 4; r++) {
      float4 vq[4];
      const float4* vrp = (const float4*)(vb + r * D_ + sl * 16);
      vq[0] = vrp[0]; vq[1] = vrp[1]; vq[2] = vrp[2]; vq[3] = vrp[3];
      const float* vv = (const float*)vq;
      float ea = e1[r][0], eb = e1[r][1];
      #pragma unroll
      for (int j = 0; j < 16; j++) {
        oacc[0][j] += ea * vv[j];
        oacc[1][j] += eb * vv[j];
      }
    }
  };

  if (b < 64) {
    int g0 = b * 32;
    const float* kc_base = cacheK + (size_t)h * P_ * D_;
    const float* vc_base = cacheV + (size_t)h * P_ * D_;
    // preload ALL nz before any store (no alias stall; static indices)
    float nzv[8];
    #pragma unroll
    for (int it = 0; it < 8; it++)
      nzv[it] = e2g[(size_t)((g0 + widx + it * 4) * 4) * 16];
    #pragma unroll
    for (int it = 0; it < 8; it++) {
      int p0 = (g0 + widx + it * 4) * 4;     // always < P_
      process(p0, kc_base + (size_t)p0 * D_, vc_base + (size_t)p0 * D_, nzv[it]);
    }
  } else if (widx < 4) {
    // new-KV tail: 4 groups (p 8192..8207), waves 0..3
    int p0 = P_ + widx * 4;
    const float* kb = ws + WS_K + ((size_t)h * 16 + widx * 4) * 128;
    const float* vb = ws + WS_V + ((size_t)h * 16 + widx * 4) * 128;
    float nz = e2g[(size_t)p0 * 16];
    process(p0, kb, vb, nz);
  }

  // ---- s1/s2: per-wave partials straight to global ----
  s1 += __shfl_xor(s1, 16, 64); s1 += __shfl_xor(s1, 32, 64);
  s2 += __shfl_xor(s2, 16, 64); s2 += __shfl_xor(s2, 32, 64);
  if (lane < 16) {
    size_t sp = (((size_t)h * 65 + b) * 4 + widx) * 16 + lane;
    ws[WS_SP1 + sp] = s1;
    ws[WS_SP2 + sp] = s2;
  }

  // ---- cross-wave O reduce: stride-17 rows (conflict-free), 2 rounds ----
  float* po = ws + WS_PO + (size_t)(h * 65 + b) * 2048;
  #pragma unroll
  for (int t = 0; t < 2; t++) {
    if (t) __syncthreads();
    float* rw = red + widx * 1088 + lane * 17;
    #pragma unroll
    for (int j = 0; j < 16; j++) rw[j] = oacc[t][j];
    __syncthreads();
    for (int e = threadIdx.x; e < 1024; e += 256) {
      int ln = e >> 4, j = e & 15;
      int phys = ln * 17 + j;
      float v = red[phys] + red[phys + 1088] + red[phys + 2176] + red[phys + 3264];
      int mo = (ln & 7) + 8 * t;
      int d = (ln >> 3) * 16 + j;
      po[mo * 128 + d] = v;
    }
  }
}

// ---------------- Kernel S: final s1/s2 sums + 1/s2 ----------------
__global__ __launch_bounds__(256) void sums_kernel(float* __restrict__ ws) {
  int tid = blockIdx.x * 256 + threadIdx.x;
  if (tid >= 512) return;
  int h = tid >> 4, m = tid & 15;
  float a = 0.f, c2 = 0.f;
  for (int i = 0; i < 260; i++) {
    a  += ws[WS_SP1 + ((size_t)h * 260 + i) * 16 + m];
    c2 += ws[WS_SP2 + ((size_t)h * 260 + i) * 16 + m];
  }
  ws[WS_S1 + tid] = a;
  ws[WS_S2 + tid] = c2;
  ws[WS_IS2 + tid] = 1.0f / c2;
}

// ---------------- Kernel D: o2 epilogue ----------------
__global__ __launch_bounds__(256) void epilogue_kernel(const float* __restrict__ ws,
                                                       float* __restrict__ out) {
  int tid = blockIdx.x * 256 + threadIdx.x;  // 0..65535
  int mm = tid >> 12, j = tid & 4095;
  int h = j >> 7, d = j & 127;
  float acc = 0.f;
  for (int b = 0; b < 65; b++)
    acc += ws[WS_PO + (size_t)(h * 65 + b) * 2048 + mm * 128 + d];
  out[tid] = acc / ws[WS_S1 + h * 16 + mm];
}

// ---------------- Kernel C2: c_out (contiguous e2t reads) ----------------
__global__ __launch_bounds__(256) void cout_kernel(const float* __restrict__ ws,
                                                   float* __restrict__ out) {
  int tid = blockIdx.x * 256 + threadIdx.x;
  if (tid >= H_ * PM_) return;
  int h = tid / PM_, p = tid - h * PM_;
  const float4* e2p = (const float4*)(ws + WS_E2 + ((size_t)h * PM_ + p) * 16);
  const float* is2 = ws + WS_IS2 + h * 16;
  float acc = 0.f;
  #pragma unroll
  for (int q = 0; q < 4; q++) {
    float4 v = e2p[q];
    acc += v.x * is2[q * 4] + v.y * is2[q * 4 + 1] + v.z * is2[q * 4 + 2] + v.w * is2[q * 4 + 3];
  }
  out[65536 + tid] = acc;
}

extern "C" void kernel_launch(void* const* d_in, const int* in_sizes, int n_in,
                              void* d_out, int out_size, void* d_ws, size_t ws_size,
                              hipStream_t stream) {
  const float* X     = (const float*)d_in[0];
  const float* Wq    = (const float*)d_in[1];
  const float* Wk    = (const float*)d_in[2];
  const float* Wv    = (const float*)d_in[3];
  const float* cK    = (const float*)d_in[4];
  const float* cV    = (const float*)d_in[5];
  const float* tau   = (const float*)d_in[6];
  const float* noise = (const float*)d_in[7];
  float* out = (float*)d_out;
  float* ws  = (float*)d_ws;

  rmsnorm_kernel<<<16, 256, 0, stream>>>(X, ws);
  proj_kernel<<<1536, 256, 0, stream>>>(Wq, Wk, Wv, ws + WS_XQ, ws);
  proj_reduce_kernel<<<768, 256, 0, stream>>>(ws);
  noise_t_kernel<<<32 * 129, 256, 0, stream>>>(noise, ws);   // after proj_reduce (E2 aliases PP)
  attn_kernel<<<32 * 65, 256, 0, stream>>>(cK, cV, tau, ws);
  sums_kernel<<<2, 256, 0, stream>>>(ws);
  epilogue_kernel<<<256, 256, 0, stream>>>(ws, out);
  cout_kernel<<<1026, 256, 0, stream>>>(ws, out);
}

// Round 9
// 299.380 us; speedup vs baseline: 3.6276x; 3.6276x over previous
//
#include <hip/hip_runtime.h>

#define M_ 16
#define H_ 32
#define D_ 128
#define P_ 8192
#define N_ 4096
#define PM_ 8208   // P + M

// workspace layout (float offsets) — no region needs pre-zeroing
#define WS_Q    0          // [32][16][128] q
#define WS_K    65536      // [32][16][128] new k
#define WS_V    131072     // [32][16][128] new v
#define WS_S1   196608     // [512]
#define WS_S2   197120     // [512]
#define WS_IS2  197632     // [512] 1/s2
#define WS_XQ   198144     // x_norm as float4 [1024][16]
#define WS_E2   263680     // e2t [32][8208][16] (h,p,m) — written by attn, read by cout
#define WS_PP   263680     // proj partials [32][16][12288] — ALIASES E2/PO (dead before attn)
#define WS_PO   4466176    // attn O partials [32][64][16][128]  (ends 8,660,480)
#define WS_SP1  8660480    // [32][64][4][16] s1 partials (ends 8,791,552)
#define WS_SP2  8791552    // [32][64][4][16]           (ends 8,922,624)
// total = 8,922,624 floats = 35.7 MB

typedef __attribute__((address_space(1))) const void gvoid_t;
typedef __attribute__((address_space(3))) void lvoid_t;

// ---------------- Kernel A: RMS norm ----------------
__global__ __launch_bounds__(256) void rmsnorm_kernel(const float* __restrict__ X,
                                                      float* __restrict__ ws) {
  int m = blockIdx.x, t = threadIdx.x;
  __shared__ float red[256];
  const float4* X4 = (const float4*)(X + (size_t)m * N_);
  float s = 0.f;
  #pragma unroll
  for (int q = 0; q < 4; q++) {
    float4 v = X4[t + q * 256];
    s += v.x * v.x + v.y * v.y + v.z * v.z + v.w * v.w;
  }
  red[t] = s;
  __syncthreads();
  for (int off = 128; off > 0; off >>= 1) {
    if (t < off) red[t] += red[t + off];
    __syncthreads();
  }
  float scale = rsqrtf(red[0] * (1.0f / N_));
  float4* xq = (float4*)(ws + WS_XQ);
  #pragma unroll
  for (int q = 0; q < 4; q++) {
    int nq = t + q * 256;
    float4 v = X4[nq];
    v.x *= scale; v.y *= scale; v.z *= scale; v.w *= scale;
    xq[nq * 16 + m] = v;  // xq[n/4][m]
  }
}

// ---------------- Kernel B: QKV projection (k-split x32) ----------------
__global__ __launch_bounds__(256, 4) void proj_kernel(const float* __restrict__ Wq,
                                                      const float* __restrict__ Wk,
                                                      const float* __restrict__ Wv,
                                                      const float* __restrict__ xr,
                                                      float* __restrict__ ws) {
  __shared__ float tile[4 * 2048];  // 8KB per wave
  int widx = threadIdx.x >> 6, lane = threadIdx.x & 63;
  int kc = blockIdx.x / 48;
  int jt = (blockIdx.x % 48) * 4 + widx;
  int jj0 = jt * 64;
  int sel = jj0 >> 12;
  int j0 = jj0 & 4095;
  const float* Wm = (sel == 0) ? Wq : ((sel == 1) ? Wk : Wv);
  int n0 = kc * 128;

  float* tl = tile + widx * 2048;
  int g8 = lane >> 3, c8 = lane & 7;
  int cq = c8 ^ g8;

  const float* gsrc[8];
  #pragma unroll
  for (int i = 0; i < 8; i++)
    gsrc[i] = Wm + (size_t)(j0 + i * 8 + g8) * N_ + n0 + cq * 4;

  const float4* tl4 = (const float4*)tl;
  int rbase = lane * 8;
  int swz = lane & 7;

  const float4* xr4 = (const float4*)xr;
  float acc[16];
  #pragma unroll
  for (int m = 0; m < 16; m++) acc[m] = 0.f;

  for (int ti = 0; ti < 4; ti++) {
    #pragma unroll
    for (int i = 0; i < 8; i++)
      __builtin_amdgcn_global_load_lds((gvoid_t*)(gsrc[i] + ti * 32),
                                       (lvoid_t*)(tl + i * 256), 16, 0, 0);
    asm volatile("s_waitcnt vmcnt(0)" ::: "memory");
    __builtin_amdgcn_sched_barrier(0);

    int nqb = (n0 >> 2) + ti * 8;
    #pragma unroll
    for (int k = 0; k < 8; k++) {
      float4 w4 = tl4[rbase + (k ^ swz)];
      int qbase = (nqb + k) * 16;
      #pragma unroll
      for (int m = 0; m < 16; m++) {
        float4 xm = xr4[qbase + m];
        acc[m] += xm.x * w4.x + xm.y * w4.y + xm.z * w4.z + xm.w * w4.w;
      }
    }
  }

  float* pp = ws + WS_PP + (size_t)kc * 16 * 12288 + jj0 + lane;
  #pragma unroll
  for (int m = 0; m < 16; m++) pp[(size_t)m * 12288] = acc[m];
}

// ---------------- Kernel B2: reduce proj partials over kc ----------------
__global__ __launch_bounds__(256) void proj_reduce_kernel(float* __restrict__ ws) {
  int tid = blockIdx.x * 256 + threadIdx.x;  // 0..196607
  int m = tid / 12288;
  int j = tid - m * 12288;
  float acc = 0.f;
  #pragma unroll
  for (int kc = 0; kc < 32; kc++)
    acc += ws[WS_PP + ((size_t)(kc * 16 + m)) * 12288 + j];
  int sel = j >> 12, jj = j & 4095;
  int h = jj >> 7, d = jj & 127;
  ws[WS_Q + sel * 65536 + (h * 16 + m) * 128 + d] = acc;
}

// ---------------- Kernel C1: attention main pass ----------------
// EXACT round-5 loop body (proven 118us @ grid 1024, VGPR=64, no spill).
// Changed only: launch geometry 2048 blocks (64/head, 8 blocks/CU), LDS
// shrunk to 17408B (two-round stride-17 O reduce), s1/s2 partials to global.
__global__ __launch_bounds__(256) void attn_kernel(const float* __restrict__ cacheK,
                                                   const float* __restrict__ cacheV,
                                                   const float* __restrict__ noise,
                                                   const float* __restrict__ taup,
                                                   float* __restrict__ ws) {
  __shared__ float red[4 * 1088];      // 17408 B: stride-17 rows
  int h = blockIdx.x >> 6, b = blockIdx.x & 63;
  int widx = threadIdx.x >> 6, lane = threadIdx.x & 63;
  int m8 = lane & 7, sl = lane >> 3;
  int rsel = lane >> 4;
  int msel = lane & 15;
  bool tb = (lane >> 3) & 1;
  bool rb0 = rsel & 1, rb1 = (rsel >> 1) & 1;
  float inv_tau = 1.0f / taup[0];

  float qv[2][16];
  #pragma unroll
  for (int t = 0; t < 2; t++) {
    const float4* qp = (const float4*)(ws + WS_Q + ((size_t)(h * 16) + m8 + 8 * t) * 128 + sl * 16);
    #pragma unroll
    for (int jq = 0; jq < 4; jq++) {
      float4 v = qp[jq];
      qv[t][jq * 4] = v.x; qv[t][jq * 4 + 1] = v.y;
      qv[t][jq * 4 + 2] = v.z; qv[t][jq * 4 + 3] = v.w;
    }
  }
  float oacc[2][16];
  #pragma unroll
  for (int t = 0; t < 2; t++)
    #pragma unroll
    for (int j = 0; j < 16; j++) oacc[t][j] = 0.f;
  float s1 = 0.f, s2 = 0.f;

  const float* nbase = noise + ((size_t)h * 16 + msel) * PM_;
  float* e2base = ws + WS_E2 + (size_t)h * PM_ * 16 + msel;
  const float* kc_base = cacheK + (size_t)h * P_ * D_;
  const float* vc_base = cacheV + (size_t)h * P_ * D_;
  const float* kn_base = ws + WS_K + (size_t)h * 16 * 128;
  const float* vn_base = ws + WS_V + (size_t)h * 16 * 128;

  // block b handles groups [start, start+cnt): 2052 = 64*32 + 4
  int start = b * 32 + (b < 4 ? b : 4);
  int cnt = 32 + (b < 4 ? 1 : 0);
  for (int gl = start + widx; gl < start + cnt; gl += 4) {
    int p0 = gl * 4;
    const float *kb, *vb;
    if (p0 < P_) { kb = kc_base + (size_t)p0 * D_; vb = vc_base + (size_t)p0 * D_; }
    else { kb = kn_base + (size_t)(p0 - P_) * D_; vb = vn_base + (size_t)(p0 - P_) * D_; }

    float nz = nbase[p0 + rsel];   // independent __restrict__ input: hoists freely

    float pr[4][2];
    #pragma unroll
    for (int r = 0; r < 4; r++) {
      float4 kq[4];
      const float4* krp = (const float4*)(kb + r * D_ + sl * 16);
      kq[0] = krp[0]; kq[1] = krp[1]; kq[2] = krp[2]; kq[3] = krp[3];
      const float* kk = (const float*)kq;
      float t0 = 0.f, t1 = 0.f;
      #pragma unroll
      for (int j = 0; j < 16; j++) { t0 += kk[j] * qv[0][j]; t1 += kk[j] * qv[1][j]; }
      pr[r][0] = t0; pr[r][1] = t1;
    }
    float cc[4][2];
    #pragma unroll
    for (int r = 0; r < 4; r++)
      #pragma unroll
      for (int t = 0; t < 2; t++) {
        float v = pr[r][t];
        v += __shfl_xor(v, 8, 64);
        v += __shfl_xor(v, 16, 64);
        v += __shfl_xor(v, 32, 64);
        cc[r][t] = v;
      }

    // static select trees — no runtime array indexing
    float a0 = tb ? cc[0][1] : cc[0][0];
    float a1 = tb ? cc[1][1] : cc[1][0];
    float a2 = tb ? cc[2][1] : cc[2][0];
    float a3 = tb ? cc[3][1] : cc[3][0];
    float b0 = rb0 ? a1 : a0;
    float b1 = rb0 ? a3 : a2;
    float myc = rb1 ? b1 : b0;

    float e2 = __expf((myc + nz) * inv_tau);
    e2base[(size_t)(p0 + rsel) * 16] = e2;
    s2 += e2;

    float e1[4][2];
    #pragma unroll
    for (int r = 0; r < 4; r++) {
      e1[r][0] = __expf(cc[r][0]);
      e1[r][1] = __expf(cc[r][1]);
    }
    float f0 = tb ? e1[0][1] : e1[0][0];
    float f1 = tb ? e1[1][1] : e1[1][0];
    float f2 = tb ? e1[2][1] : e1[2][0];
    float f3 = tb ? e1[3][1] : e1[3][0];
    float g0s = rb0 ? f1 : f0;
    float g1s = rb0 ? f3 : f2;
    s1 += rb1 ? g1s : g0s;

    #pragma unroll
    for (int r = 0; r < 4; r++) {
      float4 vq[4];
      const float4* vrp = (const float4*)(vb + r * D_ + sl * 16);
      vq[0] = vrp[0]; vq[1] = vrp[1]; vq[2] = vrp[2]; vq[3] = vrp[3];
      const float* vv = (const float*)vq;
      float ea = e1[r][0], eb = e1[r][1];
      #pragma unroll
      for (int j = 0; j < 16; j++) {
        oacc[0][j] += ea * vv[j];
        oacc[1][j] += eb * vv[j];
      }
    }
  }

  // ---- s1/s2: per-wave partials straight to global ----
  s1 += __shfl_xor(s1, 16, 64); s1 += __shfl_xor(s1, 32, 64);
  s2 += __shfl_xor(s2, 16, 64); s2 += __shfl_xor(s2, 32, 64);
  if (lane < 16) {
    size_t sp = (((size_t)h * 64 + b) * 4 + widx) * 16 + lane;
    ws[WS_SP1 + sp] = s1;
    ws[WS_SP2 + sp] = s2;
  }

  // ---- cross-wave O reduce: stride-17 rows, 2 rounds (17.4KB LDS) ----
  float* po = ws + WS_PO + (size_t)(h * 64 + b) * 2048;
  #pragma unroll
  for (int t = 0; t < 2; t++) {
    if (t) __syncthreads();
    float* rw = red + widx * 1088 + lane * 17;
    #pragma unroll
    for (int j = 0; j < 16; j++) rw[j] = oacc[t][j];
    __syncthreads();
    for (int e = threadIdx.x; e < 1024; e += 256) {
      int ln = e >> 4, j = e & 15;
      int phys = ln * 17 + j;
      float v = red[phys] + red[phys + 1088] + red[phys + 2176] + red[phys + 3264];
      int mo = (ln & 7) + 8 * t;
      int d = (ln >> 3) * 16 + j;
      po[mo * 128 + d] = v;
    }
  }
}

// ---------------- Kernel S: final s1/s2 sums + 1/s2 ----------------
__global__ __launch_bounds__(256) void sums_kernel(float* __restrict__ ws) {
  int tid = blockIdx.x * 256 + threadIdx.x;
  if (tid >= 512) return;
  int h = tid >> 4, m = tid & 15;
  float a = 0.f, c2 = 0.f;
  for (int i = 0; i < 256; i++) {
    a  += ws[WS_SP1 + ((size_t)h * 256 + i) * 16 + m];
    c2 += ws[WS_SP2 + ((size_t)h * 256 + i) * 16 + m];
  }
  ws[WS_S1 + tid] = a;
  ws[WS_S2 + tid] = c2;
  ws[WS_IS2 + tid] = 1.0f / c2;
}

// ---------------- Kernel D: o2 epilogue ----------------
__global__ __launch_bounds__(256) void epilogue_kernel(const float* __restrict__ ws,
                                                       float* __restrict__ out) {
  int tid = blockIdx.x * 256 + threadIdx.x;  // 0..65535
  int mm = tid >> 12, j = tid & 4095;
  int h = j >> 7, d = j & 127;
  float acc = 0.f;
  for (int b = 0; b < 64; b++)
    acc += ws[WS_PO + (size_t)(h * 64 + b) * 2048 + mm * 128 + d];
  out[tid] = acc / ws[WS_S1 + h * 16 + mm];
}

// ---------------- Kernel C2: c_out (contiguous e2t reads) ----------------
__global__ __launch_bounds__(256) void cout_kernel(const float* __restrict__ ws,
                                                   float* __restrict__ out) {
  int tid = blockIdx.x * 256 + threadIdx.x;
  if (tid >= H_ * PM_) return;
  int h = tid / PM_, p = tid - h * PM_;
  const float4* e2p = (const float4*)(ws + WS_E2 + ((size_t)h * PM_ + p) * 16);
  const float* is2 = ws + WS_IS2 + h * 16;
  float acc = 0.f;
  #pragma unroll
  for (int q = 0; q < 4; q++) {
    float4 v = e2p[q];
    acc += v.x * is2[q * 4] + v.y * is2[q * 4 + 1] + v.z * is2[q * 4 + 2] + v.w * is2[q * 4 + 3];
  }
  out[65536 + tid] = acc;
}

extern "C" void kernel_launch(void* const* d_in, const int* in_sizes, int n_in,
                              void* d_out, int out_size, void* d_ws, size_t ws_size,
                              hipStream_t stream) {
  const float* X     = (const float*)d_in[0];
  const float* Wq    = (const float*)d_in[1];
  const float* Wk    = (const float*)d_in[2];
  const float* Wv    = (const float*)d_in[3];
  const float* cK    = (const float*)d_in[4];
  const float* cV    = (const float*)d_in[5];
  const float* tau   = (const float*)d_in[6];
  const float* noise = (const float*)d_in[7];
  float* out = (float*)d_out;
  float* ws  = (float*)d_ws;

  rmsnorm_kernel<<<16, 256, 0, stream>>>(X, ws);
  proj_kernel<<<1536, 256, 0, stream>>>(Wq, Wk, Wv, ws + WS_XQ, ws);
  proj_reduce_kernel<<<768, 256, 0, stream>>>(ws);
  attn_kernel<<<2048, 256, 0, stream>>>(cK, cV, noise, tau, ws);
  sums_kernel<<<2, 256, 0, stream>>>(ws);
  epilogue_kernel<<<256, 256, 0, stream>>>(ws, out);
  cout_kernel<<<1026, 256, 0, stream>>>(ws, out);
}

// Round 10
// 226.290 us; speedup vs baseline: 4.7993x; 1.3230x over previous
//
#include <hip/hip_runtime.h>

#define M_ 16
#define H_ 32
#define D_ 128
#define P_ 8192
#define N_ 4096
#define PM_ 8208   // P + M

// workspace layout (float offsets) — no region needs pre-zeroing
#define WS_Q    0          // [32][16][128] q
#define WS_K    65536      // [32][16][128] new k
#define WS_V    131072     // [32][16][128] new v
#define WS_S1   196608     // [512]
#define WS_S2   197120     // [512]
#define WS_IS2  197632     // [512] 1/s2
#define WS_XQ   198144     // x_norm as float4 [1024][16]
#define WS_E2   263680     // e2t [32][8208][16] (h,p,m)  (ends 4,466,176)
#define WS_E1   4466176    // e1t [32][8208][16] (h,p,m)  (ends 8,668,672)
#define WS_PP   263680     // proj partials [32][16][12288] — ALIASES E2+E1-head (dead before qk)
#define WS_PO   8668672    // pv O partials [32][32][16][128] (ends 10,765,824)
#define WS_SP1  10765824   // [32*32][16] s1 per block (ends 10,782,208)
#define WS_SP2  10782208   // [32*32][16]              (ends 10,798,592)
// total = 10,798,592 floats = 43.2 MB

typedef __attribute__((address_space(1))) const void gvoid_t;
typedef __attribute__((address_space(3))) void lvoid_t;

// ---------------- Kernel A: RMS norm ----------------
__global__ __launch_bounds__(256) void rmsnorm_kernel(const float* __restrict__ X,
                                                      float* __restrict__ ws) {
  int m = blockIdx.x, t = threadIdx.x;
  __shared__ float red[256];
  const float4* X4 = (const float4*)(X + (size_t)m * N_);
  float s = 0.f;
  #pragma unroll
  for (int q = 0; q < 4; q++) {
    float4 v = X4[t + q * 256];
    s += v.x * v.x + v.y * v.y + v.z * v.z + v.w * v.w;
  }
  red[t] = s;
  __syncthreads();
  for (int off = 128; off > 0; off >>= 1) {
    if (t < off) red[t] += red[t + off];
    __syncthreads();
  }
  float scale = rsqrtf(red[0] * (1.0f / N_));
  float4* xq = (float4*)(ws + WS_XQ);
  #pragma unroll
  for (int q = 0; q < 4; q++) {
    int nq = t + q * 256;
    float4 v = X4[nq];
    v.x *= scale; v.y *= scale; v.z *= scale; v.w *= scale;
    xq[nq * 16 + m] = v;  // xq[n/4][m]
  }
}

// ---------------- Kernel B: QKV projection (k-split x32) ----------------
__global__ __launch_bounds__(256, 4) void proj_kernel(const float* __restrict__ Wq,
                                                      const float* __restrict__ Wk,
                                                      const float* __restrict__ Wv,
                                                      const float* __restrict__ xr,
                                                      float* __restrict__ ws) {
  __shared__ float tile[4 * 2048];  // 8KB per wave
  int widx = threadIdx.x >> 6, lane = threadIdx.x & 63;
  int kc = blockIdx.x / 48;
  int jt = (blockIdx.x % 48) * 4 + widx;
  int jj0 = jt * 64;
  int sel = jj0 >> 12;
  int j0 = jj0 & 4095;
  const float* Wm = (sel == 0) ? Wq : ((sel == 1) ? Wk : Wv);
  int n0 = kc * 128;

  float* tl = tile + widx * 2048;
  int g8 = lane >> 3, c8 = lane & 7;
  int cq = c8 ^ g8;

  const float* gsrc[8];
  #pragma unroll
  for (int i = 0; i < 8; i++)
    gsrc[i] = Wm + (size_t)(j0 + i * 8 + g8) * N_ + n0 + cq * 4;

  const float4* tl4 = (const float4*)tl;
  int rbase = lane * 8;
  int swz = lane & 7;

  const float4* xr4 = (const float4*)xr;
  float acc[16];
  #pragma unroll
  for (int m = 0; m < 16; m++) acc[m] = 0.f;

  for (int ti = 0; ti < 4; ti++) {
    #pragma unroll
    for (int i = 0; i < 8; i++)
      __builtin_amdgcn_global_load_lds((gvoid_t*)(gsrc[i] + ti * 32),
                                       (lvoid_t*)(tl + i * 256), 16, 0, 0);
    asm volatile("s_waitcnt vmcnt(0)" ::: "memory");
    __builtin_amdgcn_sched_barrier(0);

    int nqb = (n0 >> 2) + ti * 8;
    #pragma unroll
    for (int k = 0; k < 8; k++) {
      float4 w4 = tl4[rbase + (k ^ swz)];
      int qbase = (nqb + k) * 16;
      #pragma unroll
      for (int m = 0; m < 16; m++) {
        float4 xm = xr4[qbase + m];
        acc[m] += xm.x * w4.x + xm.y * w4.y + xm.z * w4.z + xm.w * w4.w;
      }
    }
  }

  float* pp = ws + WS_PP + (size_t)kc * 16 * 12288 + jj0 + lane;
  #pragma unroll
  for (int m = 0; m < 16; m++) pp[(size_t)m * 12288] = acc[m];
}

// ---------------- Kernel B2: reduce proj partials over kc ----------------
__global__ __launch_bounds__(256) void proj_reduce_kernel(float* __restrict__ ws) {
  int tid = blockIdx.x * 256 + threadIdx.x;  // 0..196607
  int m = tid / 12288;
  int j = tid - m * 12288;
  float acc = 0.f;
  #pragma unroll
  for (int kc = 0; kc < 32; kc++)
    acc += ws[WS_PP + ((size_t)(kc * 16 + m)) * 12288 + j];
  int sel = j >> 12, jj = j & 4095;
  int h = jj >> 7, d = jj & 127;
  ws[WS_Q + sel * 65536 + (h * 16 + m) * 128 + d] = acc;
}

// ---------------- Kernel C1a: QK^T + softmax numerators ----------------
// R5's QK/softmax code minus PV. Main loop: kb = cacheK unconditionally
// (restrict-clean: loads hoist past e1/e2 ws stores). Tail (b==31): 4 new-KV
// groups from WS_K. Writes e1t + e2t (coalesced 256B/wave), s1/s2 per block.
__global__ __launch_bounds__(256) void qk_kernel(const float* __restrict__ cacheK,
                                                 const float* __restrict__ noise,
                                                 const float* __restrict__ taup,
                                                 float* __restrict__ ws) {
  __shared__ float sred[2][4][16];
  int h = blockIdx.x >> 5, b = blockIdx.x & 31;
  int widx = threadIdx.x >> 6, lane = threadIdx.x & 63;
  int m8 = lane & 7, sl = lane >> 3;
  int rsel = lane >> 4;
  int msel = lane & 15;
  bool tb = (lane >> 3) & 1;
  bool rb0 = rsel & 1, rb1 = (rsel >> 1) & 1;
  bool hb = sl >> 2, sb0 = sl & 1, sb1 = (sl >> 1) & 1;
  float inv_tau = 1.0f / taup[0];

  float qv[2][16];
  #pragma unroll
  for (int t = 0; t < 2; t++) {
    const float4* qp = (const float4*)(ws + WS_Q + ((size_t)(h * 16) + m8 + 8 * t) * 128 + sl * 16);
    #pragma unroll
    for (int jq = 0; jq < 4; jq++) {
      float4 v = qp[jq];
      qv[t][jq * 4] = v.x; qv[t][jq * 4 + 1] = v.y;
      qv[t][jq * 4 + 2] = v.z; qv[t][jq * 4 + 3] = v.w;
    }
  }
  float s1 = 0.f, s2 = 0.f;

  const float* nbase = noise + ((size_t)h * 16 + msel) * PM_;
  float* e2base = ws + WS_E2 + (size_t)h * PM_ * 16 + msel;
  // e1 writer: lane covers (r = sl&3, half = sl>>2, m8)
  float* e1base = ws + WS_E1 + (size_t)h * PM_ * 16 + (sl & 3) * 16 + (sl >> 2) * 8 + m8;
  const float* kc_base = cacheK + (size_t)h * P_ * D_;

  auto qk_one = [&](int p0, const float* kb) {
    float nz = nbase[p0 + rsel];

    float pr[4][2];
    #pragma unroll
    for (int r = 0; r < 4; r++) {
      float4 kq[4];
      const float4* krp = (const float4*)(kb + r * D_ + sl * 16);
      kq[0] = krp[0]; kq[1] = krp[1]; kq[2] = krp[2]; kq[3] = krp[3];
      const float* kk = (const float*)kq;
      float t0 = 0.f, t1 = 0.f;
      #pragma unroll
      for (int j = 0; j < 16; j++) { t0 += kk[j] * qv[0][j]; t1 += kk[j] * qv[1][j]; }
      pr[r][0] = t0; pr[r][1] = t1;
    }
    float cc[4][2];
    #pragma unroll
    for (int r = 0; r < 4; r++)
      #pragma unroll
      for (int t = 0; t < 2; t++) {
        float v = pr[r][t];
        v += __shfl_xor(v, 8, 64);
        v += __shfl_xor(v, 16, 64);
        v += __shfl_xor(v, 32, 64);
        cc[r][t] = v;
      }

    // e2: lane slot (rsel, msel) — static select tree
    float a0 = tb ? cc[0][1] : cc[0][0];
    float a1 = tb ? cc[1][1] : cc[1][0];
    float a2 = tb ? cc[2][1] : cc[2][0];
    float a3 = tb ? cc[3][1] : cc[3][0];
    float b0 = rb0 ? a1 : a0;
    float b1 = rb0 ? a3 : a2;
    float myc = rb1 ? b1 : b0;
    float e2 = __expf((myc + nz) * inv_tau);
    e2base[(size_t)(p0 + rsel) * 16] = e2;
    s2 += e2;

    float e1[4][2];
    #pragma unroll
    for (int r = 0; r < 4; r++) {
      e1[r][0] = __expf(cc[r][0]);
      e1[r][1] = __expf(cc[r][1]);
    }
    // s1: slot (rsel, msel)
    float f0 = tb ? e1[0][1] : e1[0][0];
    float f1 = tb ? e1[1][1] : e1[1][0];
    float f2 = tb ? e1[2][1] : e1[2][0];
    float f3 = tb ? e1[3][1] : e1[3][0];
    float g0s = rb0 ? f1 : f0;
    float g1s = rb0 ? f3 : f2;
    s1 += rb1 ? g1s : g0s;

    // e1 store: lane (r=sl&3, half=sl>>2, m8) — 256B/wave coalesced
    float u0 = hb ? e1[0][1] : e1[0][0];
    float u1 = hb ? e1[1][1] : e1[1][0];
    float u2 = hb ? e1[2][1] : e1[2][0];
    float u3 = hb ? e1[3][1] : e1[3][0];
    float w0 = sb0 ? u1 : u0;
    float w1 = sb0 ? u3 : u2;
    float val = sb1 ? w1 : w0;
    e1base[(size_t)p0 * 16] = val;
  };

  int g0 = b * 64;
  for (int gl = widx; gl < 64; gl += 4) {        // cache-only: kb restrict-clean
    int p0 = (g0 + gl) * 4;
    qk_one(p0, kc_base + (size_t)p0 * D_);
  }
  if (b == 31) {                                  // new-KV tail: 1 group/wave
    int p0 = P_ + widx * 4;
    qk_one(p0, ws + WS_K + ((size_t)h * 16 + widx * 4) * 128);
  }

  // ---- s1/s2 block reduce (R5 pattern) ----
  s1 += __shfl_xor(s1, 16, 64); s1 += __shfl_xor(s1, 32, 64);
  s2 += __shfl_xor(s2, 16, 64); s2 += __shfl_xor(s2, 32, 64);
  if (lane < 16) { sred[0][widx][lane] = s1; sred[1][widx][lane] = s2; }
  __syncthreads();
  if (threadIdx.x < 16) {
    int mm = threadIdx.x;
    float a  = sred[0][0][mm] + sred[0][1][mm] + sred[0][2][mm] + sred[0][3][mm];
    float c2 = sred[1][0][mm] + sred[1][1][mm] + sred[1][2][mm] + sred[1][3][mm];
    ws[WS_SP1 + (size_t)(h * 32 + b) * 16 + mm] = a;
    ws[WS_SP2 + (size_t)(h * 32 + b) * 16 + mm] = c2;
  }
}

// ---------------- Kernel C1b: PV accumulate ----------------
// Main loop: ZERO stores, no shuffles, no exps — loads pipeline freely.
// vb = cacheV unconditionally (tail from WS_V in b==31 extra step).
__global__ __launch_bounds__(256) void pv_kernel(const float* __restrict__ cacheV,
                                                 const float* __restrict__ ws,
                                                 float* __restrict__ wout) {
  __shared__ float red[4 * 2048];      // 32KB rotation-swizzled reduce (R5)
  int h = blockIdx.x >> 5, b = blockIdx.x & 31;
  int widx = threadIdx.x >> 6, lane = threadIdx.x & 63;
  int m8 = lane & 7, sl = lane >> 3;

  float oacc[2][16];
  #pragma unroll
  for (int t = 0; t < 2; t++)
    #pragma unroll
    for (int j = 0; j < 16; j++) oacc[t][j] = 0.f;

  const float* e1r = ws + WS_E1 + (size_t)h * PM_ * 16 + m8;
  const float* vc_base = cacheV + (size_t)h * P_ * D_;

  auto pv_one = [&](int p0, const float* vb) {
    float ea[4], eb[4];
    #pragma unroll
    for (int r = 0; r < 4; r++) {
      ea[r] = e1r[(size_t)p0 * 16 + r * 16];
      eb[r] = e1r[(size_t)p0 * 16 + r * 16 + 8];
    }
    #pragma unroll
    for (int r = 0; r < 4; r++) {
      float4 vq[4];
      const float4* vrp = (const float4*)(vb + r * D_ + sl * 16);
      vq[0] = vrp[0]; vq[1] = vrp[1]; vq[2] = vrp[2]; vq[3] = vrp[3];
      const float* vv = (const float*)vq;
      #pragma unroll
      for (int j = 0; j < 16; j++) {
        oacc[0][j] += ea[r] * vv[j];
        oacc[1][j] += eb[r] * vv[j];
      }
    }
  };

  int g0 = b * 64;
  for (int gl = widx; gl < 64; gl += 4) {
    int p0 = (g0 + gl) * 4;
    pv_one(p0, vc_base + (size_t)p0 * D_);
  }
  if (b == 31) {
    int p0 = P_ + widx * 4;
    pv_one(p0, ws + WS_V + ((size_t)h * 16 + widx * 4) * 128);
  }

  // ---- block-level O reduce (R5 verbatim: rotation swizzle, 0 conflicts) ----
  float* rw = red + widx * 2048 + lane * 32;
  #pragma unroll
  for (int t = 0; t < 2; t++)
    #pragma unroll
    for (int j = 0; j < 16; j++) {
      int i = t * 16 + j;
      rw[(i + lane) & 31] = oacc[t][j];
    }
  __syncthreads();

  float* po = wout + WS_PO + (size_t)(h * 32 + b) * 2048;
  for (int e = threadIdx.x; e < 2048; e += 256) {
    int ln = e >> 5, i = e & 31;
    int phys = (ln << 5) + ((i + ln) & 31);
    float v = red[phys] + red[phys + 2048] + red[phys + 4096] + red[phys + 6144];
    int mo = (ln & 7) + 8 * (i >> 4);
    int d = (ln >> 3) * 16 + (i & 15);
    po[mo * 128 + d] = v;
  }
}

// ---------------- Kernel S: final s1/s2 sums + 1/s2 ----------------
__global__ __launch_bounds__(256) void sums_kernel(float* __restrict__ ws) {
  int tid = blockIdx.x * 256 + threadIdx.x;
  if (tid >= 512) return;
  int h = tid >> 4, m = tid & 15;
  float a = 0.f, c2 = 0.f;
  #pragma unroll
  for (int b = 0; b < 32; b++) {
    a  += ws[WS_SP1 + (size_t)(h * 32 + b) * 16 + m];
    c2 += ws[WS_SP2 + (size_t)(h * 32 + b) * 16 + m];
  }
  ws[WS_S1 + tid] = a;
  ws[WS_S2 + tid] = c2;
  ws[WS_IS2 + tid] = 1.0f / c2;
}

// ---------------- Kernel D: o2 epilogue ----------------
__global__ __launch_bounds__(256) void epilogue_kernel(const float* __restrict__ ws,
                                                       float* __restrict__ out) {
  int tid = blockIdx.x * 256 + threadIdx.x;  // 0..65535
  int mm = tid >> 12, j = tid & 4095;
  int h = j >> 7, d = j & 127;
  float acc = 0.f;
  #pragma unroll
  for (int b = 0; b < 32; b++)
    acc += ws[WS_PO + (size_t)(h * 32 + b) * 2048 + mm * 128 + d];
  out[tid] = acc / ws[WS_S1 + h * 16 + mm];
}

// ---------------- Kernel C2: c_out (contiguous e2t reads) ----------------
__global__ __launch_bounds__(256) void cout_kernel(const float* __restrict__ ws,
                                                   float* __restrict__ out) {
  int tid = blockIdx.x * 256 + threadIdx.x;
  if (tid >= H_ * PM_) return;
  int h = tid / PM_, p = tid - h * PM_;
  const float4* e2p = (const float4*)(ws + WS_E2 + ((size_t)h * PM_ + p) * 16);
  const float* is2 = ws + WS_IS2 + h * 16;
  float acc = 0.f;
  #pragma unroll
  for (int q = 0; q < 4; q++) {
    float4 v = e2p[q];
    acc += v.x * is2[q * 4] + v.y * is2[q * 4 + 1] + v.z * is2[q * 4 + 2] + v.w * is2[q * 4 + 3];
  }
  out[65536 + tid] = acc;
}

extern "C" void kernel_launch(void* const* d_in, const int* in_sizes, int n_in,
                              void* d_out, int out_size, void* d_ws, size_t ws_size,
                              hipStream_t stream) {
  const float* X     = (const float*)d_in[0];
  const float* Wq    = (const float*)d_in[1];
  const float* Wk    = (const float*)d_in[2];
  const float* Wv    = (const float*)d_in[3];
  const float* cK    = (const float*)d_in[4];
  const float* cV    = (const float*)d_in[5];
  const float* tau   = (const float*)d_in[6];
  const float* noise = (const float*)d_in[7];
  float* out = (float*)d_out;
  float* ws  = (float*)d_ws;

  rmsnorm_kernel<<<16, 256, 0, stream>>>(X, ws);
  proj_kernel<<<1536, 256, 0, stream>>>(Wq, Wk, Wv, ws + WS_XQ, ws);
  proj_reduce_kernel<<<768, 256, 0, stream>>>(ws);
  qk_kernel<<<1024, 256, 0, stream>>>(cK, noise, tau, ws);
  sums_kernel<<<2, 256, 0, stream>>>(ws);
  pv_kernel<<<1024, 256, 0, stream>>>(cV, ws, ws);
  epilogue_kernel<<<256, 256, 0, stream>>>(ws, out);
  cout_kernel<<<1026, 256, 0, stream>>>(ws, out);
}